// Round 1
// baseline (43.315 us; speedup 1.0000x reference)
//
#include <hip/hip_runtime.h>

// PLIF forward: x [B=16, T=16, C=128, H=32, W=32] fp32, scalar w.
// Per position: 16-step sequential LIF scan:
//   mem = w*mem + x_t; spike = (mem - 1.0 >= 0); mem = spike ? 0 : mem
// Memory-bound: 128 MiB in + 128 MiB out => ~43 us floor at 6.3 TB/s.

#define T_STEPS 16
#define CHW (128 * 32 * 32)           // 131072 elements per (b, t) slab
#define VECS_PER_B (CHW / 4)          // 32768 float4 per (b, t) slab
#define N_BATCH 16

__global__ __launch_bounds__(256) void plif_fwd_kernel(
    const float* __restrict__ x,
    const float* __restrict__ wp,
    float* __restrict__ out)
{
    const float w = wp[0];

    const int tid = blockIdx.x * blockDim.x + threadIdx.x;  // 0 .. 524287
    const int b = tid / VECS_PER_B;
    const int v = tid - b * VECS_PER_B;

    const size_t base = (size_t)b * ((size_t)T_STEPS * CHW) + (size_t)v * 4;
    const float4* __restrict__ xin  = reinterpret_cast<const float4*>(x + base);
    float4* __restrict__ sout       = reinterpret_cast<float4*>(out + base);

    float m0 = 0.0f, m1 = 0.0f, m2 = 0.0f, m3 = 0.0f;

#pragma unroll
    for (int t = 0; t < T_STEPS; ++t) {
        const float4 xv = xin[(size_t)t * VECS_PER_B];

        // mem = w*mem + x  -- separate mul/add rounding (match non-fma XLA CPU ref)
        m0 = __fadd_rn(__fmul_rn(w, m0), xv.x);
        m1 = __fadd_rn(__fmul_rn(w, m1), xv.y);
        m2 = __fadd_rn(__fmul_rn(w, m2), xv.z);
        m3 = __fadd_rn(__fmul_rn(w, m3), xv.w);

        // spike = H(mem - v_th); mirror the reference's subtract-then-compare
        const float d0 = __fsub_rn(m0, 1.0f);
        const float d1 = __fsub_rn(m1, 1.0f);
        const float d2 = __fsub_rn(m2, 1.0f);
        const float d3 = __fsub_rn(m3, 1.0f);

        float4 s;
        s.x = (d0 >= 0.0f) ? 1.0f : 0.0f;
        s.y = (d1 >= 0.0f) ? 1.0f : 0.0f;
        s.z = (d2 >= 0.0f) ? 1.0f : 0.0f;
        s.w = (d3 >= 0.0f) ? 1.0f : 0.0f;

        // mem = mem * (1 - spike): exact select (spiking mem >= 1 > 0 -> exactly 0)
        m0 = (d0 >= 0.0f) ? 0.0f : m0;
        m1 = (d1 >= 0.0f) ? 0.0f : m1;
        m2 = (d2 >= 0.0f) ? 0.0f : m2;
        m3 = (d3 >= 0.0f) ? 0.0f : m3;

        sout[(size_t)t * VECS_PER_B] = s;
    }
}

extern "C" void kernel_launch(void* const* d_in, const int* in_sizes, int n_in,
                              void* d_out, int out_size, void* d_ws, size_t ws_size,
                              hipStream_t stream)
{
    const float* x = (const float*)d_in[0];
    const float* w = (const float*)d_in[1];
    float* out = (float*)d_out;

    const int total_threads = N_BATCH * VECS_PER_B;  // 524288
    const int block = 256;
    const int grid = total_threads / block;          // 2048

    plif_fwd_kernel<<<grid, block, 0, stream>>>(x, w, out);
}